// Round 23
// baseline (1175.462 us; speedup 1.0000x reference)
//
#include <hip/hip_runtime.h>
#include <hip/hip_bf16.h>

typedef __hip_bfloat16 hbf16;
typedef __attribute__((ext_vector_type(8))) short bfrag8;
typedef __attribute__((ext_vector_type(4))) short short4v;
typedef __attribute__((ext_vector_type(4))) float f32x4;

#define BATCH 16
#define HH 512
#define WW 512
#define HWSZ (HH * WW)
#define STRIPH 128
#define NSTEPS (STRIPH + 24)

__device__ __forceinline__ short f2bf(float f) {
    hbf16 h = __float2bfloat16(f);
    return *(short*)&h;
}

__device__ __forceinline__ float blockSum(float v) {
#pragma unroll
    for (int o = 32; o > 0; o >>= 1) v += __shfl_down(v, o, 64);
    __shared__ float sh[4];
    const int lane = threadIdx.x & 63, wid = threadIdx.x >> 6;
    if (lane == 0) sh[wid] = v;
    __syncthreads();
    float r = 0.f;
    if (threadIdx.x == 0) r = sh[0] + sh[1] + sh[2] + sh[3];
    __syncthreads();
    return r;
}

// ---------------------------------------------------------------------------
// Full 8-layer predictor, software-pipelined (R21/R22-verified structure).
// 512 thr = 8 waves; wave w owns layer w; one barrier per step; skew 2.
// Layout: R21's [slot][PW][16ch] windows (measured 33M conflicts vs 53M for
// the R22 half-split — cross-group aliasing made the "fix" worse).
// STRIPH=128 (R22's win): 512 blocks = 2 resident/CU, one residency wave.
// Windows: fin 4x80x2ch; window l (l=0..6) 4 x (78-2l) x 16ch, packed in aW
// at short-offset 64*l*(79-l). LDS 65.8 KB -> 2 blocks/CU.
// ---------------------------------------------------------------------------
__global__ __launch_bounds__(512) void k_pred8(
    const float* __restrict__ p0, long long s0,
    const float* __restrict__ p1, long long s1,
    const float* __restrict__ xsrc, long long xstride,
    float* __restrict__ outp,
    const float* __restrict__ w0, const float* __restrict__ b0,
    const float* __restrict__ w1, const float* __restrict__ b1,
    const float* __restrict__ w2, const float* __restrict__ b2,
    const float* __restrict__ w3, const float* __restrict__ b3,
    const float* __restrict__ w4, const float* __restrict__ b4,
    const float* __restrict__ w5, const float* __restrict__ b5,
    const float* __restrict__ w6, const float* __restrict__ b6,
    const float* __restrict__ w7, const float* __restrict__ b7)
{
    __shared__ short finW[4 * 80 * 2];     //  1,280 B
    __shared__ short aW[4 * 504 * 16];     // 64,512 B (a0..a6 packed)

    const int tid = threadIdx.x, lane = tid & 63, wv = tid >> 6;
    const int tx0 = blockIdx.x * 64, Y0 = blockIdx.y * STRIPH;
    const long long b = blockIdx.z;
    const float* pa = p0 + b * s0;
    const float* pb = p1 + b * s1;
    const float* xb = xsrc + b * xstride;
    float* ob = outp + b * (long long)HWSZ;

    const int arow = lane & 15, grp = lane >> 4, lx = lane & 15;
    const int cib = (grp & 1) * 8, kofb = grp >> 1;
    const int c0 = grp * 4;

    // per-wave window geometry (layer wv): in = window wv-1, out = window wv
    const short* inw = aW + 64 * (wv - 1) * (80 - wv);   // valid for wv>=1
    short* outw = aW + 64 * wv * (79 - wv);              // valid for wv<=6
    const int IW = 80 - 2 * wv, OW = 78 - 2 * wv;

    // per-wave weight fragments + tap offsets
    bfrag8 myf[5];
    int dys[5], dxs[5];
    float mb0 = 0.f, mb1 = 0.f, mb2 = 0.f, mb3 = 0.f;
#pragma unroll
    for (int s = 0; s < 5; ++s) {
        const int koff = 2 * s + kofb;
        const int kc = (koff < 9) ? koff : 8;
        dys[s] = kc / 3; dxs[s] = kc - dys[s] * 3;
#pragma unroll
        for (int j = 0; j < 8; ++j) myf[s][j] = 0;
    }
    if (wv == 0) {
#pragma unroll
        for (int j = 0; j < 8; ++j) {
            const int k = grp * 8 + j;
            myf[0][j] = (k < 18) ? f2bf(w0[arow * 18 + (k & 1) * 9 + (k >> 1)])
                                 : (short)0;
        }
        mb0 = b0[c0]; mb1 = b0[c0 + 1]; mb2 = b0[c0 + 2]; mb3 = b0[c0 + 3];
    } else {
        const float* wp = (wv == 1) ? w1 : (wv == 2) ? w2 : (wv == 3) ? w3 :
                          (wv == 4) ? w4 : (wv == 5) ? w5 : (wv == 6) ? w6 : w7;
        const float* bp = (wv == 1) ? b1 : (wv == 2) ? b2 : (wv == 3) ? b3 :
                          (wv == 4) ? b4 : (wv == 5) ? b5 : (wv == 6) ? b6 : b7;
        const bool rmask = (wv < 7) || (arow < 3);
#pragma unroll
        for (int s = 0; s < 5; ++s) {
            const int koff = 2 * s + kofb;
#pragma unroll
            for (int j = 0; j < 8; ++j)
                myf[s][j] = (rmask && koff < 9)
                              ? f2bf(wp[(arow * 16 + cib + j) * 9 + koff])
                              : (short)0;
        }
        if (wv == 7) {
            mb0 = (grp == 0) ? bp[0] : 0.f;
            mb1 = (grp == 0) ? bp[1] : 0.f;
            mb2 = (grp == 0) ? bp[2] : 0.f;
        } else {
            mb0 = bp[c0]; mb1 = bp[c0 + 1]; mb2 = bp[c0 + 2]; mb3 = bp[c0 + 3];
        }
    }

    // generic conv row (layers 1..6): inw/IW -> outw/OW, global row gr
    auto CONVG = [&](int gr) {
        const bool rok = ((unsigned)gr < (unsigned)HH);
        const int halo = (OW - 64) >> 1;
        const int rslot = (gr & 3) * OW;
        const int rm1 = ((gr - 1) & 3) * IW, r00 = (gr & 3) * IW,
                  rp1 = ((gr + 1) & 3) * IW;
#pragma unroll
        for (int c = 0; c < 5; ++c) {
            const int xr = c * 16 + lx;
            const int xc = (xr < OW) ? xr : (OW - 1);
            f32x4 a = { mb0, mb1, mb2, mb3 };
#pragma unroll
            for (int s = 0; s < 5; ++s) {
                const int rof = (dys[s] == 0) ? rm1 : ((dys[s] == 2) ? rp1 : r00);
                const bfrag8 q = *(const bfrag8*)&inw[(rof + xc + dxs[s]) * 16 + cib];
                a = __builtin_amdgcn_mfma_f32_16x16x32_bf16(myf[s], q, a, 0, 0, 0);
            }
            if (xr < OW) {
                const int gx = tx0 - halo + xr;
                const bool ok = rok && ((unsigned)gx < (unsigned)WW);
                short4v st;
#pragma unroll
                for (int i = 0; i < 4; ++i) {
                    float r = a[i]; r = (r >= 0.f) ? r : 0.01f * r;
                    st[i] = ok ? f2bf(r) : (short)0;
                }
                *(short4v*)&outw[(rslot + xr) * 16 + c0] = st;
            }
        }
    };

    // L0 row (wave 0): fin gather (K=18) -> window 0 (width 78, halo 7)
    auto L0ROW = [&](int gr) {
        const bool rok = ((unsigned)gr < (unsigned)HH);
        const int rslot = (gr & 3) * 78;
        const int rm1 = ((gr - 1) & 3) * 80, r00 = (gr & 3) * 80,
                  rp1 = ((gr + 1) & 3) * 80;
        short* a0w = aW;   // window 0 at offset 0
#pragma unroll
        for (int c = 0; c < 5; ++c) {
            const int xr = c * 16 + lx;
            const int xc = (xr < 78) ? xr : 77;
            bfrag8 bf;
#pragma unroll
            for (int j = 0; j < 8; ++j) {
                const int k = grp * 8 + j;
                short v = 0;
                if (k < 18) {
                    const int tap = k >> 1, dy = tap / 3, dx = tap - dy * 3;
                    const int ro = (dy == 0) ? rm1 : ((dy == 2) ? rp1 : r00);
                    v = finW[(ro + xc + dx) * 2 + (k & 1)];
                }
                bf[j] = v;
            }
            f32x4 a = { mb0, mb1, mb2, mb3 };
            a = __builtin_amdgcn_mfma_f32_16x16x32_bf16(myf[0], bf, a, 0, 0, 0);
            if (xr < 78) {
                const int gx = tx0 - 7 + xr;
                const bool ok = rok && ((unsigned)gx < (unsigned)WW);
                short4v st;
#pragma unroll
                for (int i = 0; i < 4; ++i) {
                    float r = a[i]; r = (r >= 0.f) ? r : 0.01f * r;
                    st[i] = ok ? f2bf(r) : (short)0;
                }
                *(short4v*)&a0w[(rslot + xr) * 16 + c0] = st;
            }
        }
    };

    // L7 row (wave 7): window 6 (width 66) -> clip/median3/(x - med) -> global
    auto OUT7 = [&](int gr) {
        const int rm1 = ((gr - 1) & 3) * 66, r00 = (gr & 3) * 66,
                  rp1 = ((gr + 1) & 3) * 66;
#pragma unroll
        for (int c = 0; c < 4; ++c) {
            const int o = c * 16 + lx;
            f32x4 a = { mb0, mb1, mb2, 0.f };
#pragma unroll
            for (int s = 0; s < 5; ++s) {
                const int rof = (dys[s] == 0) ? rm1 : ((dys[s] == 2) ? rp1 : r00);
                const bfrag8 q = *(const bfrag8*)&inw[(rof + o + dxs[s]) * 16 + cib];
                a = __builtin_amdgcn_mfma_f32_16x16x32_bf16(myf[s], q, a, 0, 0, 0);
            }
            if (grp == 0) {
                float y0 = fminf(fmaxf(a[0], -1.f), 1.f);
                float y1 = fminf(fmaxf(a[1], -1.f), 1.f);
                float y2 = fminf(fmaxf(a[2], -1.f), 1.f);
                float med = fmaxf(fminf(y0, fmaxf(y1, y2)), fminf(y1, y2));
                const long long pix = (long long)gr * WW + tx0 + o;
                ob[pix] = xb[pix] - med;
            }
        }
    };

    // main pipeline: NSTEPS steps, ONE barrier each
    for (int S = 0; S < NSTEPS; ++S) {
        if (wv == 7) {
            const int R = Y0 - 8 + S;
            const bool doStage = (S < STRIPH + 16);
            float v0 = 0.f, v1 = 0.f, v2 = 0.f;
            if (doStage) {
                const int i0 = lane, i1 = lane + 64, i2 = lane + 128;
                {
                    const int xx = i0 >> 1, ci = i0 & 1, gx = tx0 - 8 + xx;
                    if ((unsigned)R < (unsigned)HH && (unsigned)gx < (unsigned)WW)
                        v0 = (ci ? pb : pa)[R * WW + gx];
                }
                {
                    const int xx = i1 >> 1, ci = i1 & 1, gx = tx0 - 8 + xx;
                    if ((unsigned)R < (unsigned)HH && (unsigned)gx < (unsigned)WW)
                        v1 = (ci ? pb : pa)[R * WW + gx];
                }
                if (i2 < 160) {
                    const int xx = i2 >> 1, ci = i2 & 1, gx = tx0 - 8 + xx;
                    if ((unsigned)R < (unsigned)HH && (unsigned)gx < (unsigned)WW)
                        v2 = (ci ? pb : pa)[R * WW + gx];
                }
            }
            const int r7 = Y0 - 24 + S;
            if (r7 >= Y0 && r7 <= Y0 + STRIPH - 1) OUT7(r7);
            if (doStage) {
                const int base = (R & 3) * 80;
                const int i0 = lane, i1 = lane + 64, i2 = lane + 128;
                finW[(base + (i0 >> 1)) * 2 + (i0 & 1)] = f2bf(v0);
                finW[(base + (i1 >> 1)) * 2 + (i1 & 1)] = f2bf(v1);
                if (i2 < 160)
                    finW[(base + (i2 >> 1)) * 2 + (i2 & 1)] = f2bf(v2);
            }
        } else if (wv == 0) {
            const int r0 = Y0 - 10 + S;
            if (r0 >= Y0 - 7 && r0 <= Y0 + STRIPH + 6) L0ROW(r0);
        } else {
            const int r = Y0 - 10 + S - 2 * wv;
            if (r >= Y0 - (7 - wv) && r <= Y0 + STRIPH + 6 - wv) CONVG(r);
        }
        __syncthreads();
    }
}

// ---------------------------------------------------------------------------
// Stats over x: float4 loads, per-wave LDS histograms, SSQ
// ---------------------------------------------------------------------------
__global__ __launch_bounds__(256) void k_stats_x(
    const float* __restrict__ x, unsigned* __restrict__ hist, float* __restrict__ sums)
{
    const int p = blockIdx.y;
    const f32x4* src = (const f32x4*)(x + (long long)p * HWSZ);
    __shared__ unsigned h[4][256];
    for (int i = threadIdx.x; i < 1024; i += 256) ((unsigned*)h)[i] = 0;
    __syncthreads();
    const int wid = threadIdx.x >> 6;

    float ss = 0.f;
    for (int i4 = blockIdx.x * 256 + threadIdx.x; i4 < HWSZ / 4; i4 += gridDim.x * 256) {
        const f32x4 v4 = src[i4];
#pragma unroll
        for (int e = 0; e < 4; ++e) {
            const float v = v4[e];
            ss += v * v;
            if (v >= -1.f && v <= 1.f) {
                int idx = (int)floorf((v + 1.f) * 128.f);
                idx = min(max(idx, 0), 255);
                atomicAdd(&h[wid][idx], 1u);
            }
        }
    }
    __syncthreads();
    const unsigned t = h[0][threadIdx.x] + h[1][threadIdx.x] +
                       h[2][threadIdx.x] + h[3][threadIdx.x];
    if (t) atomicAdd(&hist[p * 256 + threadIdx.x], t);

    float bs = blockSum(ss);
    if (threadIdx.x == 0) atomicAdd(&sums[0], bs);
}

// ---------------------------------------------------------------------------
// Stats over deltas, all 3 planes in one dispatch (z = channel).
// ---------------------------------------------------------------------------
__global__ __launch_bounds__(256) void k_stats_delta(
    const float* __restrict__ planes,
    unsigned* __restrict__ hist, float* __restrict__ sums)
{
    const int b = blockIdx.y, cz = blockIdx.z;
    const float* P = planes + ((long long)cz * BATCH + b) * HWSZ;
    const int row = b * 3 + cz;
    __shared__ unsigned h[4][256];
    for (int i = threadIdx.x; i < 1024; i += 256) ((unsigned*)h)[i] = 0;
    __syncthreads();
    const int wid = threadIdx.x >> 6;

    float ss = 0.f;
    for (int i4 = blockIdx.x * 256 + threadIdx.x; i4 < HWSZ / 4; i4 += gridDim.x * 256) {
        const int i0 = i4 * 4;
        const int y = i0 >> 9, x0 = i0 & (WW - 1);
        const f32x4 cur = ((const f32x4*)P)[i4];
        f32x4 up = { 0.f, 0.f, 0.f, 0.f };
        if (y) up = ((const f32x4*)P)[i4 - (WW / 4)];
        const float left = x0 ? P[i0 - 1] : 0.f;
        const float upl = (x0 && y) ? P[i0 - WW - 1] : 0.f;
#pragma unroll
        for (int e = 0; e < 4; ++e) {
            const float v = cur[e];
            const float n = up[e];
            const float wv = e ? cur[e - 1] : left;
            const float nw = e ? up[e - 1] : upl;
            float pr = n + wv - nw;
            pr = fminf(fmaxf(pr, fminf(n, wv)), fmaxf(n, wv));
            const float d = v - pr;
            ss += d * d;
            if (d >= -1.f && d <= 1.f) {
                int idx = (int)floorf((d + 1.f) * 128.f);
                idx = min(max(idx, 0), 255);
                atomicAdd(&h[wid][idx], 1u);
            }
        }
    }
    __syncthreads();
    const unsigned t = h[0][threadIdx.x] + h[1][threadIdx.x] +
                       h[2][threadIdx.x] + h[3][threadIdx.x];
    if (t) atomicAdd(&hist[row * 256 + threadIdx.x], t);

    float bs = blockSum(ss);
    if (threadIdx.x == 0) atomicAdd(&sums[1], bs);
}

// ---------------------------------------------------------------------------
// Finalize: entropies + the 4 output scalars
// ---------------------------------------------------------------------------
__global__ __launch_bounds__(256) void k_finalize(
    const unsigned* __restrict__ hist0, const unsigned* __restrict__ hist1,
    const float* __restrict__ sums, float* __restrict__ out)
{
    float e0 = 0.f, e1 = 0.f;
    for (int i = threadIdx.x; i < 48 * 256; i += 256) {
        float p0 = (float)hist0[i] * (1.0f / HWSZ);
        if (p0 > 0.f) e0 -= p0 * log2f(p0);
        float p1 = (float)hist1[i] * (1.0f / HWSZ);
        if (p1 > 0.f) e1 -= p1 * log2f(p1);
    }
    float t0 = blockSum(e0);
    float t1 = blockSum(e1);
    if (threadIdx.x == 0) {
        const float N = (float)BATCH * 3.f * (float)HWSZ;
        out[0] = 128.f * sqrtf(sums[1] / N);   // loss1 (deltas)
        out[1] = 128.f * sqrtf(sums[0] / N);   // loss0 (x)
        out[2] = t0 * (1.f / (8.f * 48.f));    // invcr0
        out[3] = t1 * (1.f / (8.f * 48.f));    // invcr1
    }
}

// ---------------------------------------------------------------------------
extern "C" void kernel_launch(void* const* d_in, const int* in_sizes, int n_in,
                              void* d_out, int out_size, void* d_ws, size_t ws_size,
                              hipStream_t stream) {
    const float* x = (const float*)d_in[0];
    const float* w[8];
    const float* bs[8];
    for (int i = 0; i < 8; ++i) {
        w[i]  = (const float*)d_in[1 + 2 * i];
        bs[i] = (const float*)d_in[2 + 2 * i];
    }

    // Workspace: planes (50.33 MB) + hists + sums only — no activation buffer.
    char* ws = (char*)d_ws;
    size_t o = 0;
    float* rpl = (float*)(ws + o); o += (size_t)BATCH * HWSZ * 4;
    float* gpl = (float*)(ws + o); o += (size_t)BATCH * HWSZ * 4;
    float* bpl = (float*)(ws + o); o += (size_t)BATCH * HWSZ * 4;
    unsigned* hist0 = (unsigned*)(ws + o); o += 48 * 256 * 4;
    unsigned* hist1 = (unsigned*)(ws + o); o += 48 * 256 * 4;
    float* sums = (float*)(ws + o); o += 256;

    hipMemsetAsync(hist0, 0, 48 * 256 * 4 * 2 + 256, stream);

    const dim3 gq(WW / 64, HH / STRIPH, BATCH);

    auto predictor = [&](const float* pa, long long sa, const float* pb, long long sb,
                         const float* xs, float* outp) {
        k_pred8<<<gq, 512, 0, stream>>>(
            pa, sa, pb, sb, xs, 3LL * HWSZ, outp,
            w[0], bs[0], w[1], bs[1], w[2], bs[2], w[3], bs[3],
            w[4], bs[4], w[5], bs[5], w[6], bs[6], w[7], bs[7]);
    };

    // r = x_r - pred(g, b);  g = x_g - pred(r, b);  b = x_b - pred(r, g)
    predictor(x + 1LL * HWSZ, 3LL * HWSZ, x + 2LL * HWSZ, 3LL * HWSZ,
              x + 0LL * HWSZ, rpl);
    predictor(rpl, (long long)HWSZ, x + 2LL * HWSZ, 3LL * HWSZ,
              x + 1LL * HWSZ, gpl);
    predictor(rpl, (long long)HWSZ, gpl, (long long)HWSZ,
              x + 2LL * HWSZ, bpl);

    const dim3 sgrid(64, 48);
    k_stats_x<<<sgrid, 256, 0, stream>>>(x, hist0, sums);
    const dim3 dgrid(64, BATCH, 3);
    k_stats_delta<<<dgrid, 256, 0, stream>>>(rpl, hist1, sums);

    k_finalize<<<1, 256, 0, stream>>>(hist0, hist1, sums, (float*)d_out);
}

// Round 24
// 1082.592 us; speedup vs baseline: 1.0858x; 1.0858x over previous
//
#include <hip/hip_runtime.h>
#include <hip/hip_bf16.h>

typedef __hip_bfloat16 hbf16;
typedef __attribute__((ext_vector_type(8))) short bfrag8;
typedef __attribute__((ext_vector_type(4))) short short4v;
typedef __attribute__((ext_vector_type(4))) float f32x4;

#define BATCH 16
#define HH 512
#define WW 512
#define HWSZ (HH * WW)
#define STRIPH 128
#define NSTEPS (STRIPH + 24)

__device__ __forceinline__ short f2bf(float f) {
    hbf16 h = __float2bfloat16(f);
    return *(short*)&h;
}

__device__ __forceinline__ float blockSum(float v) {
#pragma unroll
    for (int o = 32; o > 0; o >>= 1) v += __shfl_down(v, o, 64);
    __shared__ float sh[4];
    const int lane = threadIdx.x & 63, wid = threadIdx.x >> 6;
    if (lane == 0) sh[wid] = v;
    __syncthreads();
    float r = 0.f;
    if (threadIdx.x == 0) r = sh[0] + sh[1] + sh[2] + sh[3];
    __syncthreads();
    return r;
}

// ---------------------------------------------------------------------------
// Full 8-layer predictor, software-pipelined (R21/R22-verified structure).
// 512 thr = 8 waves; wave w owns layer w; one barrier per step; skew 2.
// R24 trims: (a) L0 gather uses paired u32 fin reads (even k: taps of j=2t,
// 2t+1 coincide, ci-pair contiguous) -> 20 LDS ops/row instead of 40 on the
// straggler wave; (b) leaky via fmaxf(r, 0.01r).
// Windows: fin 4x80x2ch; window l (l=0..6) 4 x (78-2l) x 16ch, packed in aW
// at short-offset 64*l*(79-l). LDS 65.8 KB -> 2 blocks/CU.
// ---------------------------------------------------------------------------
__global__ __launch_bounds__(512) void k_pred8(
    const float* __restrict__ p0, long long s0,
    const float* __restrict__ p1, long long s1,
    const float* __restrict__ xsrc, long long xstride,
    float* __restrict__ outp,
    const float* __restrict__ w0, const float* __restrict__ b0,
    const float* __restrict__ w1, const float* __restrict__ b1,
    const float* __restrict__ w2, const float* __restrict__ b2,
    const float* __restrict__ w3, const float* __restrict__ b3,
    const float* __restrict__ w4, const float* __restrict__ b4,
    const float* __restrict__ w5, const float* __restrict__ b5,
    const float* __restrict__ w6, const float* __restrict__ b6,
    const float* __restrict__ w7, const float* __restrict__ b7)
{
    __shared__ short finW[4 * 80 * 2];     //  1,280 B
    __shared__ short aW[4 * 504 * 16];     // 64,512 B (a0..a6 packed)

    const int tid = threadIdx.x, lane = tid & 63, wv = tid >> 6;
    const int tx0 = blockIdx.x * 64, Y0 = blockIdx.y * STRIPH;
    const long long b = blockIdx.z;
    const float* pa = p0 + b * s0;
    const float* pb = p1 + b * s1;
    const float* xb = xsrc + b * xstride;
    float* ob = outp + b * (long long)HWSZ;

    const int arow = lane & 15, grp = lane >> 4, lx = lane & 15;
    const int cib = (grp & 1) * 8, kofb = grp >> 1;
    const int c0 = grp * 4;

    // per-wave window geometry (layer wv): in = window wv-1, out = window wv
    const short* inw = aW + 64 * (wv - 1) * (80 - wv);   // valid for wv>=1
    short* outw = aW + 64 * wv * (79 - wv);              // valid for wv<=6
    const int IW = 80 - 2 * wv, OW = 78 - 2 * wv;

    // per-wave weight fragments + tap offsets
    bfrag8 myf[5];
    int dys[5], dxs[5];
    float mb0 = 0.f, mb1 = 0.f, mb2 = 0.f, mb3 = 0.f;
#pragma unroll
    for (int s = 0; s < 5; ++s) {
        const int koff = 2 * s + kofb;
        const int kc = (koff < 9) ? koff : 8;
        dys[s] = kc / 3; dxs[s] = kc - dys[s] * 3;
#pragma unroll
        for (int j = 0; j < 8; ++j) myf[s][j] = 0;
    }
    if (wv == 0) {
#pragma unroll
        for (int j = 0; j < 8; ++j) {
            const int k = grp * 8 + j;
            myf[0][j] = (k < 18) ? f2bf(w0[arow * 18 + (k & 1) * 9 + (k >> 1)])
                                 : (short)0;
        }
        mb0 = b0[c0]; mb1 = b0[c0 + 1]; mb2 = b0[c0 + 2]; mb3 = b0[c0 + 3];
    } else {
        const float* wp = (wv == 1) ? w1 : (wv == 2) ? w2 : (wv == 3) ? w3 :
                          (wv == 4) ? w4 : (wv == 5) ? w5 : (wv == 6) ? w6 : w7;
        const float* bp = (wv == 1) ? b1 : (wv == 2) ? b2 : (wv == 3) ? b3 :
                          (wv == 4) ? b4 : (wv == 5) ? b5 : (wv == 6) ? b6 : b7;
        const bool rmask = (wv < 7) || (arow < 3);
#pragma unroll
        for (int s = 0; s < 5; ++s) {
            const int koff = 2 * s + kofb;
#pragma unroll
            for (int j = 0; j < 8; ++j)
                myf[s][j] = (rmask && koff < 9)
                              ? f2bf(wp[(arow * 16 + cib + j) * 9 + koff])
                              : (short)0;
        }
        if (wv == 7) {
            mb0 = (grp == 0) ? bp[0] : 0.f;
            mb1 = (grp == 0) ? bp[1] : 0.f;
            mb2 = (grp == 0) ? bp[2] : 0.f;
        } else {
            mb0 = bp[c0]; mb1 = bp[c0 + 1]; mb2 = bp[c0 + 2]; mb3 = bp[c0 + 3];
        }
    }

    // generic conv row (layers 1..6): inw/IW -> outw/OW, global row gr
    auto CONVG = [&](int gr) {
        const bool rok = ((unsigned)gr < (unsigned)HH);
        const int halo = (OW - 64) >> 1;
        const int rslot = (gr & 3) * OW;
        const int rm1 = ((gr - 1) & 3) * IW, r00 = (gr & 3) * IW,
                  rp1 = ((gr + 1) & 3) * IW;
#pragma unroll
        for (int c = 0; c < 5; ++c) {
            const int xr = c * 16 + lx;
            const int xc = (xr < OW) ? xr : (OW - 1);
            f32x4 a = { mb0, mb1, mb2, mb3 };
#pragma unroll
            for (int s = 0; s < 5; ++s) {
                const int rof = (dys[s] == 0) ? rm1 : ((dys[s] == 2) ? rp1 : r00);
                const bfrag8 q = *(const bfrag8*)&inw[(rof + xc + dxs[s]) * 16 + cib];
                a = __builtin_amdgcn_mfma_f32_16x16x32_bf16(myf[s], q, a, 0, 0, 0);
            }
            if (xr < OW) {
                const int gx = tx0 - halo + xr;
                const bool ok = rok && ((unsigned)gx < (unsigned)WW);
                short4v st;
#pragma unroll
                for (int i = 0; i < 4; ++i) {
                    const float r = fmaxf(a[i], 0.01f * a[i]);   // leaky
                    st[i] = ok ? f2bf(r) : (short)0;
                }
                *(short4v*)&outw[(rslot + xr) * 16 + c0] = st;
            }
        }
    };

    // L0 row (wave 0): fin gather (K=18, paired u32 reads) -> window 0
    auto L0ROW = [&](int gr) {
        const bool rok = ((unsigned)gr < (unsigned)HH);
        const int rslot = (gr & 3) * 78;
        const int rm1 = ((gr - 1) & 3) * 80, r00 = (gr & 3) * 80,
                  rp1 = ((gr + 1) & 3) * 80;
        short* a0w = aW;   // window 0 at offset 0
#pragma unroll
        for (int c = 0; c < 5; ++c) {
            const int xr = c * 16 + lx;
            const int xc = (xr < 78) ? xr : 77;
            bfrag8 bf;
#pragma unroll
            for (int t = 0; t < 4; ++t) {
                const int k = grp * 8 + 2 * t;     // even; k,k+1 share tap
                if (k < 18) {
                    const int tap = k >> 1, dy = tap / 3, dx = tap - dy * 3;
                    const int ro = (dy == 0) ? rm1 : ((dy == 2) ? rp1 : r00);
                    const unsigned u = *(const unsigned*)&finW[(ro + xc + dx) * 2];
                    bf[2 * t]     = (short)(u & 0xffffu);
                    bf[2 * t + 1] = (short)(u >> 16);
                } else {
                    bf[2 * t] = 0; bf[2 * t + 1] = 0;
                }
            }
            f32x4 a = { mb0, mb1, mb2, mb3 };
            a = __builtin_amdgcn_mfma_f32_16x16x32_bf16(myf[0], bf, a, 0, 0, 0);
            if (xr < 78) {
                const int gx = tx0 - 7 + xr;
                const bool ok = rok && ((unsigned)gx < (unsigned)WW);
                short4v st;
#pragma unroll
                for (int i = 0; i < 4; ++i) {
                    const float r = fmaxf(a[i], 0.01f * a[i]);   // leaky
                    st[i] = ok ? f2bf(r) : (short)0;
                }
                *(short4v*)&a0w[(rslot + xr) * 16 + c0] = st;
            }
        }
    };

    // L7 row (wave 7): window 6 (width 66) -> clip/median3/(x - med) -> global
    auto OUT7 = [&](int gr) {
        const int rm1 = ((gr - 1) & 3) * 66, r00 = (gr & 3) * 66,
                  rp1 = ((gr + 1) & 3) * 66;
#pragma unroll
        for (int c = 0; c < 4; ++c) {
            const int o = c * 16 + lx;
            f32x4 a = { mb0, mb1, mb2, 0.f };
#pragma unroll
            for (int s = 0; s < 5; ++s) {
                const int rof = (dys[s] == 0) ? rm1 : ((dys[s] == 2) ? rp1 : r00);
                const bfrag8 q = *(const bfrag8*)&inw[(rof + o + dxs[s]) * 16 + cib];
                a = __builtin_amdgcn_mfma_f32_16x16x32_bf16(myf[s], q, a, 0, 0, 0);
            }
            if (grp == 0) {
                float y0 = fminf(fmaxf(a[0], -1.f), 1.f);
                float y1 = fminf(fmaxf(a[1], -1.f), 1.f);
                float y2 = fminf(fmaxf(a[2], -1.f), 1.f);
                float med = fmaxf(fminf(y0, fmaxf(y1, y2)), fminf(y1, y2));
                const long long pix = (long long)gr * WW + tx0 + o;
                ob[pix] = xb[pix] - med;
            }
        }
    };

    // main pipeline: NSTEPS steps, ONE barrier each
    for (int S = 0; S < NSTEPS; ++S) {
        if (wv == 7) {
            const int R = Y0 - 8 + S;
            const bool doStage = (S < STRIPH + 16);
            float v0 = 0.f, v1 = 0.f, v2 = 0.f;
            if (doStage) {
                const int i0 = lane, i1 = lane + 64, i2 = lane + 128;
                {
                    const int xx = i0 >> 1, ci = i0 & 1, gx = tx0 - 8 + xx;
                    if ((unsigned)R < (unsigned)HH && (unsigned)gx < (unsigned)WW)
                        v0 = (ci ? pb : pa)[R * WW + gx];
                }
                {
                    const int xx = i1 >> 1, ci = i1 & 1, gx = tx0 - 8 + xx;
                    if ((unsigned)R < (unsigned)HH && (unsigned)gx < (unsigned)WW)
                        v1 = (ci ? pb : pa)[R * WW + gx];
                }
                if (i2 < 160) {
                    const int xx = i2 >> 1, ci = i2 & 1, gx = tx0 - 8 + xx;
                    if ((unsigned)R < (unsigned)HH && (unsigned)gx < (unsigned)WW)
                        v2 = (ci ? pb : pa)[R * WW + gx];
                }
            }
            const int r7 = Y0 - 24 + S;
            if (r7 >= Y0 && r7 <= Y0 + STRIPH - 1) OUT7(r7);
            if (doStage) {
                const int base = (R & 3) * 80;
                const int i0 = lane, i1 = lane + 64, i2 = lane + 128;
                finW[(base + (i0 >> 1)) * 2 + (i0 & 1)] = f2bf(v0);
                finW[(base + (i1 >> 1)) * 2 + (i1 & 1)] = f2bf(v1);
                if (i2 < 160)
                    finW[(base + (i2 >> 1)) * 2 + (i2 & 1)] = f2bf(v2);
            }
        } else if (wv == 0) {
            const int r0 = Y0 - 10 + S;
            if (r0 >= Y0 - 7 && r0 <= Y0 + STRIPH + 6) L0ROW(r0);
        } else {
            const int r = Y0 - 10 + S - 2 * wv;
            if (r >= Y0 - (7 - wv) && r <= Y0 + STRIPH + 6 - wv) CONVG(r);
        }
        __syncthreads();
    }
}

// ---------------------------------------------------------------------------
// Stats over x: float4 loads, per-wave LDS histograms, SSQ
// ---------------------------------------------------------------------------
__global__ __launch_bounds__(256) void k_stats_x(
    const float* __restrict__ x, unsigned* __restrict__ hist, float* __restrict__ sums)
{
    const int p = blockIdx.y;
    const f32x4* src = (const f32x4*)(x + (long long)p * HWSZ);
    __shared__ unsigned h[4][256];
    for (int i = threadIdx.x; i < 1024; i += 256) ((unsigned*)h)[i] = 0;
    __syncthreads();
    const int wid = threadIdx.x >> 6;

    float ss = 0.f;
    for (int i4 = blockIdx.x * 256 + threadIdx.x; i4 < HWSZ / 4; i4 += gridDim.x * 256) {
        const f32x4 v4 = src[i4];
#pragma unroll
        for (int e = 0; e < 4; ++e) {
            const float v = v4[e];
            ss += v * v;
            if (v >= -1.f && v <= 1.f) {
                int idx = (int)floorf((v + 1.f) * 128.f);
                idx = min(max(idx, 0), 255);
                atomicAdd(&h[wid][idx], 1u);
            }
        }
    }
    __syncthreads();
    const unsigned t = h[0][threadIdx.x] + h[1][threadIdx.x] +
                       h[2][threadIdx.x] + h[3][threadIdx.x];
    if (t) atomicAdd(&hist[p * 256 + threadIdx.x], t);

    float bs = blockSum(ss);
    if (threadIdx.x == 0) atomicAdd(&sums[0], bs);
}

// ---------------------------------------------------------------------------
// Stats over deltas, all 3 planes in one dispatch (z = channel).
// ---------------------------------------------------------------------------
__global__ __launch_bounds__(256) void k_stats_delta(
    const float* __restrict__ planes,
    unsigned* __restrict__ hist, float* __restrict__ sums)
{
    const int b = blockIdx.y, cz = blockIdx.z;
    const float* P = planes + ((long long)cz * BATCH + b) * HWSZ;
    const int row = b * 3 + cz;
    __shared__ unsigned h[4][256];
    for (int i = threadIdx.x; i < 1024; i += 256) ((unsigned*)h)[i] = 0;
    __syncthreads();
    const int wid = threadIdx.x >> 6;

    float ss = 0.f;
    for (int i4 = blockIdx.x * 256 + threadIdx.x; i4 < HWSZ / 4; i4 += gridDim.x * 256) {
        const int i0 = i4 * 4;
        const int y = i0 >> 9, x0 = i0 & (WW - 1);
        const f32x4 cur = ((const f32x4*)P)[i4];
        f32x4 up = { 0.f, 0.f, 0.f, 0.f };
        if (y) up = ((const f32x4*)P)[i4 - (WW / 4)];
        const float left = x0 ? P[i0 - 1] : 0.f;
        const float upl = (x0 && y) ? P[i0 - WW - 1] : 0.f;
#pragma unroll
        for (int e = 0; e < 4; ++e) {
            const float v = cur[e];
            const float n = up[e];
            const float wv = e ? cur[e - 1] : left;
            const float nw = e ? up[e - 1] : upl;
            float pr = n + wv - nw;
            pr = fminf(fmaxf(pr, fminf(n, wv)), fmaxf(n, wv));
            const float d = v - pr;
            ss += d * d;
            if (d >= -1.f && d <= 1.f) {
                int idx = (int)floorf((d + 1.f) * 128.f);
                idx = min(max(idx, 0), 255);
                atomicAdd(&h[wid][idx], 1u);
            }
        }
    }
    __syncthreads();
    const unsigned t = h[0][threadIdx.x] + h[1][threadIdx.x] +
                       h[2][threadIdx.x] + h[3][threadIdx.x];
    if (t) atomicAdd(&hist[row * 256 + threadIdx.x], t);

    float bs = blockSum(ss);
    if (threadIdx.x == 0) atomicAdd(&sums[1], bs);
}

// ---------------------------------------------------------------------------
// Finalize: entropies + the 4 output scalars
// ---------------------------------------------------------------------------
__global__ __launch_bounds__(256) void k_finalize(
    const unsigned* __restrict__ hist0, const unsigned* __restrict__ hist1,
    const float* __restrict__ sums, float* __restrict__ out)
{
    float e0 = 0.f, e1 = 0.f;
    for (int i = threadIdx.x; i < 48 * 256; i += 256) {
        float p0 = (float)hist0[i] * (1.0f / HWSZ);
        if (p0 > 0.f) e0 -= p0 * log2f(p0);
        float p1 = (float)hist1[i] * (1.0f / HWSZ);
        if (p1 > 0.f) e1 -= p1 * log2f(p1);
    }
    float t0 = blockSum(e0);
    float t1 = blockSum(e1);
    if (threadIdx.x == 0) {
        const float N = (float)BATCH * 3.f * (float)HWSZ;
        out[0] = 128.f * sqrtf(sums[1] / N);   // loss1 (deltas)
        out[1] = 128.f * sqrtf(sums[0] / N);   // loss0 (x)
        out[2] = t0 * (1.f / (8.f * 48.f));    // invcr0
        out[3] = t1 * (1.f / (8.f * 48.f));    // invcr1
    }
}

// ---------------------------------------------------------------------------
extern "C" void kernel_launch(void* const* d_in, const int* in_sizes, int n_in,
                              void* d_out, int out_size, void* d_ws, size_t ws_size,
                              hipStream_t stream) {
    const float* x = (const float*)d_in[0];
    const float* w[8];
    const float* bs[8];
    for (int i = 0; i < 8; ++i) {
        w[i]  = (const float*)d_in[1 + 2 * i];
        bs[i] = (const float*)d_in[2 + 2 * i];
    }

    // Workspace: planes (50.33 MB) + hists + sums only — no activation buffer.
    char* ws = (char*)d_ws;
    size_t o = 0;
    float* rpl = (float*)(ws + o); o += (size_t)BATCH * HWSZ * 4;
    float* gpl = (float*)(ws + o); o += (size_t)BATCH * HWSZ * 4;
    float* bpl = (float*)(ws + o); o += (size_t)BATCH * HWSZ * 4;
    unsigned* hist0 = (unsigned*)(ws + o); o += 48 * 256 * 4;
    unsigned* hist1 = (unsigned*)(ws + o); o += 48 * 256 * 4;
    float* sums = (float*)(ws + o); o += 256;

    hipMemsetAsync(hist0, 0, 48 * 256 * 4 * 2 + 256, stream);

    const dim3 gq(WW / 64, HH / STRIPH, BATCH);

    auto predictor = [&](const float* pa, long long sa, const float* pb, long long sb,
                         const float* xs, float* outp) {
        k_pred8<<<gq, 512, 0, stream>>>(
            pa, sa, pb, sb, xs, 3LL * HWSZ, outp,
            w[0], bs[0], w[1], bs[1], w[2], bs[2], w[3], bs[3],
            w[4], bs[4], w[5], bs[5], w[6], bs[6], w[7], bs[7]);
    };

    // r = x_r - pred(g, b);  g = x_g - pred(r, b);  b = x_b - pred(r, g)
    predictor(x + 1LL * HWSZ, 3LL * HWSZ, x + 2LL * HWSZ, 3LL * HWSZ,
              x + 0LL * HWSZ, rpl);
    predictor(rpl, (long long)HWSZ, x + 2LL * HWSZ, 3LL * HWSZ,
              x + 1LL * HWSZ, gpl);
    predictor(rpl, (long long)HWSZ, gpl, (long long)HWSZ,
              x + 2LL * HWSZ, bpl);

    const dim3 sgrid(64, 48);
    k_stats_x<<<sgrid, 256, 0, stream>>>(x, hist0, sums);
    const dim3 dgrid(64, BATCH, 3);
    k_stats_delta<<<dgrid, 256, 0, stream>>>(rpl, hist1, sums);

    k_finalize<<<1, 256, 0, stream>>>(hist0, hist1, sums, (float*)d_out);
}

// Round 25
// 1034.585 us; speedup vs baseline: 1.1362x; 1.0464x over previous
//
#include <hip/hip_runtime.h>
#include <hip/hip_bf16.h>

typedef __hip_bfloat16 hbf16;
typedef __attribute__((ext_vector_type(8))) short bfrag8;
typedef __attribute__((ext_vector_type(4))) short short4v;
typedef __attribute__((ext_vector_type(4))) float f32x4;

#define BATCH 16
#define HH 512
#define WW 512
#define HWSZ (HH * WW)
#define STRIPH 128
#define NSTEPS (STRIPH + 24)

__device__ __forceinline__ short f2bf(float f) {
    hbf16 h = __float2bfloat16(f);
    return *(short*)&h;
}

__device__ __forceinline__ float blockSum(float v) {
#pragma unroll
    for (int o = 32; o > 0; o >>= 1) v += __shfl_down(v, o, 64);
    __shared__ float sh[4];
    const int lane = threadIdx.x & 63, wid = threadIdx.x >> 6;
    if (lane == 0) sh[wid] = v;
    __syncthreads();
    float r = 0.f;
    if (threadIdx.x == 0) r = sh[0] + sh[1] + sh[2] + sh[3];
    __syncthreads();
    return r;
}

// ---------------------------------------------------------------------------
// Full 8-layer predictor, software-pipelined (R21/R22/R24-verified).
// 512 thr = 8 waves; wave w owns layer w; one barrier per step; skew 2.
// R25: wave-7 staging prefetched ONE STEP AHEAD (loads for row R(S+1) issued
// at step S, consumed at S+1 -> full step of latency cover); staging
// addresses/plane-select hoisted (ci identical for all 3 elements);
// CONVG/L0ROW column clamp folded for always-in-range columns 0-3.
// Windows: fin 4x80x2ch; window l (l=0..6) 4 x (78-2l) x 16ch, packed in aW
// at short-offset 64*l*(79-l). LDS 65.8 KB -> 2 blocks/CU.
// ---------------------------------------------------------------------------
__global__ __launch_bounds__(512) void k_pred8(
    const float* __restrict__ p0, long long s0,
    const float* __restrict__ p1, long long s1,
    const float* __restrict__ xsrc, long long xstride,
    float* __restrict__ outp,
    const float* __restrict__ w0, const float* __restrict__ b0,
    const float* __restrict__ w1, const float* __restrict__ b1,
    const float* __restrict__ w2, const float* __restrict__ b2,
    const float* __restrict__ w3, const float* __restrict__ b3,
    const float* __restrict__ w4, const float* __restrict__ b4,
    const float* __restrict__ w5, const float* __restrict__ b5,
    const float* __restrict__ w6, const float* __restrict__ b6,
    const float* __restrict__ w7, const float* __restrict__ b7)
{
    __shared__ short finW[4 * 80 * 2];     //  1,280 B
    __shared__ short aW[4 * 504 * 16];     // 64,512 B (a0..a6 packed)

    const int tid = threadIdx.x, lane = tid & 63, wv = tid >> 6;
    const int tx0 = blockIdx.x * 64, Y0 = blockIdx.y * STRIPH;
    const long long b = blockIdx.z;
    const float* pa = p0 + b * s0;
    const float* pb = p1 + b * s1;
    const float* xb = xsrc + b * xstride;
    float* ob = outp + b * (long long)HWSZ;

    const int arow = lane & 15, grp = lane >> 4, lx = lane & 15;
    const int cib = (grp & 1) * 8, kofb = grp >> 1;
    const int c0 = grp * 4;

    // per-wave window geometry (layer wv): in = window wv-1, out = window wv
    const short* inw = aW + 64 * (wv - 1) * (80 - wv);   // valid for wv>=1
    short* outw = aW + 64 * wv * (79 - wv);              // valid for wv<=6
    const int IW = 80 - 2 * wv, OW = 78 - 2 * wv;

    // per-wave weight fragments + tap offsets
    bfrag8 myf[5];
    int dys[5], dxs[5];
    float mb0 = 0.f, mb1 = 0.f, mb2 = 0.f, mb3 = 0.f;
#pragma unroll
    for (int s = 0; s < 5; ++s) {
        const int koff = 2 * s + kofb;
        const int kc = (koff < 9) ? koff : 8;
        dys[s] = kc / 3; dxs[s] = kc - dys[s] * 3;
#pragma unroll
        for (int j = 0; j < 8; ++j) myf[s][j] = 0;
    }
    if (wv == 0) {
#pragma unroll
        for (int j = 0; j < 8; ++j) {
            const int k = grp * 8 + j;
            myf[0][j] = (k < 18) ? f2bf(w0[arow * 18 + (k & 1) * 9 + (k >> 1)])
                                 : (short)0;
        }
        mb0 = b0[c0]; mb1 = b0[c0 + 1]; mb2 = b0[c0 + 2]; mb3 = b0[c0 + 3];
    } else {
        const float* wp = (wv == 1) ? w1 : (wv == 2) ? w2 : (wv == 3) ? w3 :
                          (wv == 4) ? w4 : (wv == 5) ? w5 : (wv == 6) ? w6 : w7;
        const float* bp = (wv == 1) ? b1 : (wv == 2) ? b2 : (wv == 3) ? b3 :
                          (wv == 4) ? b4 : (wv == 5) ? b5 : (wv == 6) ? b6 : b7;
        const bool rmask = (wv < 7) || (arow < 3);
#pragma unroll
        for (int s = 0; s < 5; ++s) {
            const int koff = 2 * s + kofb;
#pragma unroll
            for (int j = 0; j < 8; ++j)
                myf[s][j] = (rmask && koff < 9)
                              ? f2bf(wp[(arow * 16 + cib + j) * 9 + koff])
                              : (short)0;
        }
        if (wv == 7) {
            mb0 = (grp == 0) ? bp[0] : 0.f;
            mb1 = (grp == 0) ? bp[1] : 0.f;
            mb2 = (grp == 0) ? bp[2] : 0.f;
        } else {
            mb0 = bp[c0]; mb1 = bp[c0 + 1]; mb2 = bp[c0 + 2]; mb3 = bp[c0 + 3];
        }
    }

    // wave-7 hoisted staging geometry (ci identical for all 3 elements)
    const int sxx0 = lane >> 1, sci0 = lane & 1;
    const float* sp0 = sci0 ? pb : pa;
    const int sgx0 = tx0 - 8 + sxx0;
    const int sgx1 = sgx0 + 32;
    const int sgx2 = sgx0 + 64;
    const bool gok0 = ((unsigned)sgx0 < (unsigned)WW);
    const bool gok1 = ((unsigned)sgx1 < (unsigned)WW);
    const bool gok2 = (lane < 32) && ((unsigned)sgx2 < (unsigned)WW);

    // generic conv row (layers 1..6): inw/IW -> outw/OW, global row gr
    auto CONVG = [&](int gr) {
        const bool rok = ((unsigned)gr < (unsigned)HH);
        const int halo = (OW - 64) >> 1;
        const int rslot = (gr & 3) * OW;
        const int rm1 = ((gr - 1) & 3) * IW, r00 = (gr & 3) * IW,
                  rp1 = ((gr + 1) & 3) * IW;
#pragma unroll
        for (int c = 0; c < 5; ++c) {
            const int xr = c * 16 + lx;
            const int xc = (c < 4) ? xr : ((xr < OW) ? xr : (OW - 1));
            f32x4 a = { mb0, mb1, mb2, mb3 };
#pragma unroll
            for (int s = 0; s < 5; ++s) {
                const int rof = (dys[s] == 0) ? rm1 : ((dys[s] == 2) ? rp1 : r00);
                const bfrag8 q = *(const bfrag8*)&inw[(rof + xc + dxs[s]) * 16 + cib];
                a = __builtin_amdgcn_mfma_f32_16x16x32_bf16(myf[s], q, a, 0, 0, 0);
            }
            if (xr < OW) {
                const int gx = tx0 - halo + xr;
                const bool ok = rok && ((unsigned)gx < (unsigned)WW);
                short4v st;
#pragma unroll
                for (int i = 0; i < 4; ++i) {
                    const float r = fmaxf(a[i], 0.01f * a[i]);   // leaky
                    st[i] = ok ? f2bf(r) : (short)0;
                }
                *(short4v*)&outw[(rslot + xr) * 16 + c0] = st;
            }
        }
    };

    // L0 row (wave 0): fin gather (K=18, paired u32 reads) -> window 0
    auto L0ROW = [&](int gr) {
        const bool rok = ((unsigned)gr < (unsigned)HH);
        const int rslot = (gr & 3) * 78;
        const int rm1 = ((gr - 1) & 3) * 80, r00 = (gr & 3) * 80,
                  rp1 = ((gr + 1) & 3) * 80;
        short* a0w = aW;   // window 0 at offset 0
#pragma unroll
        for (int c = 0; c < 5; ++c) {
            const int xr = c * 16 + lx;
            const int xc = (c < 4) ? xr : ((xr < 78) ? xr : 77);
            bfrag8 bf;
#pragma unroll
            for (int t = 0; t < 4; ++t) {
                const int k = grp * 8 + 2 * t;     // even; k,k+1 share tap
                if (k < 18) {
                    const int tap = k >> 1, dy = tap / 3, dx = tap - dy * 3;
                    const int ro = (dy == 0) ? rm1 : ((dy == 2) ? rp1 : r00);
                    const unsigned u = *(const unsigned*)&finW[(ro + xc + dx) * 2];
                    bf[2 * t]     = (short)(u & 0xffffu);
                    bf[2 * t + 1] = (short)(u >> 16);
                } else {
                    bf[2 * t] = 0; bf[2 * t + 1] = 0;
                }
            }
            f32x4 a = { mb0, mb1, mb2, mb3 };
            a = __builtin_amdgcn_mfma_f32_16x16x32_bf16(myf[0], bf, a, 0, 0, 0);
            if (xr < 78) {
                const int gx = tx0 - 7 + xr;
                const bool ok = rok && ((unsigned)gx < (unsigned)WW);
                short4v st;
#pragma unroll
                for (int i = 0; i < 4; ++i) {
                    const float r = fmaxf(a[i], 0.01f * a[i]);   // leaky
                    st[i] = ok ? f2bf(r) : (short)0;
                }
                *(short4v*)&a0w[(rslot + xr) * 16 + c0] = st;
            }
        }
    };

    // L7 row (wave 7): window 6 (width 66) -> clip/median3/(x - med) -> global
    auto OUT7 = [&](int gr) {
        const int rm1 = ((gr - 1) & 3) * 66, r00 = (gr & 3) * 66,
                  rp1 = ((gr + 1) & 3) * 66;
#pragma unroll
        for (int c = 0; c < 4; ++c) {
            const int o = c * 16 + lx;
            f32x4 a = { mb0, mb1, mb2, 0.f };
#pragma unroll
            for (int s = 0; s < 5; ++s) {
                const int rof = (dys[s] == 0) ? rm1 : ((dys[s] == 2) ? rp1 : r00);
                const bfrag8 q = *(const bfrag8*)&inw[(rof + o + dxs[s]) * 16 + cib];
                a = __builtin_amdgcn_mfma_f32_16x16x32_bf16(myf[s], q, a, 0, 0, 0);
            }
            if (grp == 0) {
                float y0 = fminf(fmaxf(a[0], -1.f), 1.f);
                float y1 = fminf(fmaxf(a[1], -1.f), 1.f);
                float y2 = fminf(fmaxf(a[2], -1.f), 1.f);
                float med = fmaxf(fminf(y0, fmaxf(y1, y2)), fminf(y1, y2));
                const long long pix = (long long)gr * WW + tx0 + o;
                ob[pix] = xb[pix] - med;
            }
        }
    };

    // wave-7 prefetch registers (row R(S) values, loaded during step S-1)
    float pv0 = 0.f, pv1 = 0.f, pv2 = 0.f;
    if (wv == 7) {
        const int R0 = Y0 - 8;          // row for S=0
        if ((unsigned)R0 < (unsigned)HH) {
            const float* rowp = sp0 + (long long)R0 * WW;
            if (gok0) pv0 = rowp[sgx0];
            if (gok1) pv1 = rowp[sgx1];
            if (gok2) pv2 = rowp[sgx2];
        }
    }

    // main pipeline: NSTEPS steps, ONE barrier each
    for (int S = 0; S < NSTEPS; ++S) {
        if (wv == 7) {
            const int r7 = Y0 - 24 + S;
            if (r7 >= Y0 && r7 <= Y0 + STRIPH - 1) OUT7(r7);
            if (S < STRIPH + 16) {
                const int base = ((Y0 - 8 + S) & 3) * 80;
                finW[(base + sxx0) * 2 + sci0] = f2bf(pv0);
                finW[(base + sxx0 + 32) * 2 + sci0] = f2bf(pv1);
                if (lane < 32)
                    finW[(base + sxx0 + 64) * 2 + sci0] = f2bf(pv2);
            }
            if (S + 1 < STRIPH + 16) {   // prefetch row for step S+1
                const int Rn = Y0 - 7 + S;
                pv0 = 0.f; pv1 = 0.f; pv2 = 0.f;
                if ((unsigned)Rn < (unsigned)HH) {
                    const float* rowp = sp0 + (long long)Rn * WW;
                    if (gok0) pv0 = rowp[sgx0];
                    if (gok1) pv1 = rowp[sgx1];
                    if (gok2) pv2 = rowp[sgx2];
                }
            }
        } else if (wv == 0) {
            const int r0 = Y0 - 10 + S;
            if (r0 >= Y0 - 7 && r0 <= Y0 + STRIPH + 6) L0ROW(r0);
        } else {
            const int r = Y0 - 10 + S - 2 * wv;
            if (r >= Y0 - (7 - wv) && r <= Y0 + STRIPH + 6 - wv) CONVG(r);
        }
        __syncthreads();
    }
}

// ---------------------------------------------------------------------------
// Stats over x: float4 loads, per-wave LDS histograms, SSQ
// ---------------------------------------------------------------------------
__global__ __launch_bounds__(256) void k_stats_x(
    const float* __restrict__ x, unsigned* __restrict__ hist, float* __restrict__ sums)
{
    const int p = blockIdx.y;
    const f32x4* src = (const f32x4*)(x + (long long)p * HWSZ);
    __shared__ unsigned h[4][256];
    for (int i = threadIdx.x; i < 1024; i += 256) ((unsigned*)h)[i] = 0;
    __syncthreads();
    const int wid = threadIdx.x >> 6;

    float ss = 0.f;
    for (int i4 = blockIdx.x * 256 + threadIdx.x; i4 < HWSZ / 4; i4 += gridDim.x * 256) {
        const f32x4 v4 = src[i4];
#pragma unroll
        for (int e = 0; e < 4; ++e) {
            const float v = v4[e];
            ss += v * v;
            if (v >= -1.f && v <= 1.f) {
                int idx = (int)floorf((v + 1.f) * 128.f);
                idx = min(max(idx, 0), 255);
                atomicAdd(&h[wid][idx], 1u);
            }
        }
    }
    __syncthreads();
    const unsigned t = h[0][threadIdx.x] + h[1][threadIdx.x] +
                       h[2][threadIdx.x] + h[3][threadIdx.x];
    if (t) atomicAdd(&hist[p * 256 + threadIdx.x], t);

    float bs = blockSum(ss);
    if (threadIdx.x == 0) atomicAdd(&sums[0], bs);
}

// ---------------------------------------------------------------------------
// Stats over deltas, all 3 planes in one dispatch (z = channel).
// ---------------------------------------------------------------------------
__global__ __launch_bounds__(256) void k_stats_delta(
    const float* __restrict__ planes,
    unsigned* __restrict__ hist, float* __restrict__ sums)
{
    const int b = blockIdx.y, cz = blockIdx.z;
    const float* P = planes + ((long long)cz * BATCH + b) * HWSZ;
    const int row = b * 3 + cz;
    __shared__ unsigned h[4][256];
    for (int i = threadIdx.x; i < 1024; i += 256) ((unsigned*)h)[i] = 0;
    __syncthreads();
    const int wid = threadIdx.x >> 6;

    float ss = 0.f;
    for (int i4 = blockIdx.x * 256 + threadIdx.x; i4 < HWSZ / 4; i4 += gridDim.x * 256) {
        const int i0 = i4 * 4;
        const int y = i0 >> 9, x0 = i0 & (WW - 1);
        const f32x4 cur = ((const f32x4*)P)[i4];
        f32x4 up = { 0.f, 0.f, 0.f, 0.f };
        if (y) up = ((const f32x4*)P)[i4 - (WW / 4)];
        const float left = x0 ? P[i0 - 1] : 0.f;
        const float upl = (x0 && y) ? P[i0 - WW - 1] : 0.f;
#pragma unroll
        for (int e = 0; e < 4; ++e) {
            const float v = cur[e];
            const float n = up[e];
            const float wv = e ? cur[e - 1] : left;
            const float nw = e ? up[e - 1] : upl;
            float pr = n + wv - nw;
            pr = fminf(fmaxf(pr, fminf(n, wv)), fmaxf(n, wv));
            const float d = v - pr;
            ss += d * d;
            if (d >= -1.f && d <= 1.f) {
                int idx = (int)floorf((d + 1.f) * 128.f);
                idx = min(max(idx, 0), 255);
                atomicAdd(&h[wid][idx], 1u);
            }
        }
    }
    __syncthreads();
    const unsigned t = h[0][threadIdx.x] + h[1][threadIdx.x] +
                       h[2][threadIdx.x] + h[3][threadIdx.x];
    if (t) atomicAdd(&hist[row * 256 + threadIdx.x], t);

    float bs = blockSum(ss);
    if (threadIdx.x == 0) atomicAdd(&sums[1], bs);
}

// ---------------------------------------------------------------------------
// Finalize: entropies + the 4 output scalars
// ---------------------------------------------------------------------------
__global__ __launch_bounds__(256) void k_finalize(
    const unsigned* __restrict__ hist0, const unsigned* __restrict__ hist1,
    const float* __restrict__ sums, float* __restrict__ out)
{
    float e0 = 0.f, e1 = 0.f;
    for (int i = threadIdx.x; i < 48 * 256; i += 256) {
        float p0 = (float)hist0[i] * (1.0f / HWSZ);
        if (p0 > 0.f) e0 -= p0 * log2f(p0);
        float p1 = (float)hist1[i] * (1.0f / HWSZ);
        if (p1 > 0.f) e1 -= p1 * log2f(p1);
    }
    float t0 = blockSum(e0);
    float t1 = blockSum(e1);
    if (threadIdx.x == 0) {
        const float N = (float)BATCH * 3.f * (float)HWSZ;
        out[0] = 128.f * sqrtf(sums[1] / N);   // loss1 (deltas)
        out[1] = 128.f * sqrtf(sums[0] / N);   // loss0 (x)
        out[2] = t0 * (1.f / (8.f * 48.f));    // invcr0
        out[3] = t1 * (1.f / (8.f * 48.f));    // invcr1
    }
}

// ---------------------------------------------------------------------------
extern "C" void kernel_launch(void* const* d_in, const int* in_sizes, int n_in,
                              void* d_out, int out_size, void* d_ws, size_t ws_size,
                              hipStream_t stream) {
    const float* x = (const float*)d_in[0];
    const float* w[8];
    const float* bs[8];
    for (int i = 0; i < 8; ++i) {
        w[i]  = (const float*)d_in[1 + 2 * i];
        bs[i] = (const float*)d_in[2 + 2 * i];
    }

    // Workspace: planes (50.33 MB) + hists + sums only — no activation buffer.
    char* ws = (char*)d_ws;
    size_t o = 0;
    float* rpl = (float*)(ws + o); o += (size_t)BATCH * HWSZ * 4;
    float* gpl = (float*)(ws + o); o += (size_t)BATCH * HWSZ * 4;
    float* bpl = (float*)(ws + o); o += (size_t)BATCH * HWSZ * 4;
    unsigned* hist0 = (unsigned*)(ws + o); o += 48 * 256 * 4;
    unsigned* hist1 = (unsigned*)(ws + o); o += 48 * 256 * 4;
    float* sums = (float*)(ws + o); o += 256;

    hipMemsetAsync(hist0, 0, 48 * 256 * 4 * 2 + 256, stream);

    const dim3 gq(WW / 64, HH / STRIPH, BATCH);

    auto predictor = [&](const float* pa, long long sa, const float* pb, long long sb,
                         const float* xs, float* outp) {
        k_pred8<<<gq, 512, 0, stream>>>(
            pa, sa, pb, sb, xs, 3LL * HWSZ, outp,
            w[0], bs[0], w[1], bs[1], w[2], bs[2], w[3], bs[3],
            w[4], bs[4], w[5], bs[5], w[6], bs[6], w[7], bs[7]);
    };

    // r = x_r - pred(g, b);  g = x_g - pred(r, b);  b = x_b - pred(r, g)
    predictor(x + 1LL * HWSZ, 3LL * HWSZ, x + 2LL * HWSZ, 3LL * HWSZ,
              x + 0LL * HWSZ, rpl);
    predictor(rpl, (long long)HWSZ, x + 2LL * HWSZ, 3LL * HWSZ,
              x + 1LL * HWSZ, gpl);
    predictor(rpl, (long long)HWSZ, gpl, (long long)HWSZ,
              x + 2LL * HWSZ, bpl);

    const dim3 sgrid(64, 48);
    k_stats_x<<<sgrid, 256, 0, stream>>>(x, hist0, sums);
    const dim3 dgrid(64, BATCH, 3);
    k_stats_delta<<<dgrid, 256, 0, stream>>>(rpl, hist1, sums);

    k_finalize<<<1, 256, 0, stream>>>(hist0, hist1, sums, (float*)d_out);
}

// Round 26
// 1021.457 us; speedup vs baseline: 1.1508x; 1.0129x over previous
//
#include <hip/hip_runtime.h>
#include <hip/hip_bf16.h>

typedef __hip_bfloat16 hbf16;
typedef __attribute__((ext_vector_type(8))) short bfrag8;
typedef __attribute__((ext_vector_type(4))) short short4v;
typedef __attribute__((ext_vector_type(4))) float f32x4;

#define BATCH 16
#define HH 512
#define WW 512
#define HWSZ (HH * WW)
#define STRIPH 128
#define NSTEPS (STRIPH + 24)

__device__ __forceinline__ short f2bf(float f) {
    hbf16 h = __float2bfloat16(f);
    return *(short*)&h;
}

__device__ __forceinline__ float blockSum(float v) {
#pragma unroll
    for (int o = 32; o > 0; o >>= 1) v += __shfl_down(v, o, 64);
    __shared__ float sh[4];
    const int lane = threadIdx.x & 63, wid = threadIdx.x >> 6;
    if (lane == 0) sh[wid] = v;
    __syncthreads();
    float r = 0.f;
    if (threadIdx.x == 0) r = sh[0] + sh[1] + sh[2] + sh[3];
    __syncthreads();
    return r;
}

// ---------------------------------------------------------------------------
// Full 8-layer predictor, software-pipelined (R21/R22/R24/R25-verified).
// 512 thr = 8 waves; wave w owns layer w; one barrier per step; skew 2.
// R26: s_setprio(1) around each row's compute cluster (CONVG/L0ROW/OUT7);
// staging + prefetch remain prio 0, so the conv critical path wins LDS-port
// and issue arbitration (T5 mechanism: role-diverse waves).
// Windows: fin 4x80x2ch; window l (l=0..6) 4 x (78-2l) x 16ch, packed in aW
// at short-offset 64*l*(79-l). LDS 65.8 KB -> 2 blocks/CU.
// ---------------------------------------------------------------------------
__global__ __launch_bounds__(512) void k_pred8(
    const float* __restrict__ p0, long long s0,
    const float* __restrict__ p1, long long s1,
    const float* __restrict__ xsrc, long long xstride,
    float* __restrict__ outp,
    const float* __restrict__ w0, const float* __restrict__ b0,
    const float* __restrict__ w1, const float* __restrict__ b1,
    const float* __restrict__ w2, const float* __restrict__ b2,
    const float* __restrict__ w3, const float* __restrict__ b3,
    const float* __restrict__ w4, const float* __restrict__ b4,
    const float* __restrict__ w5, const float* __restrict__ b5,
    const float* __restrict__ w6, const float* __restrict__ b6,
    const float* __restrict__ w7, const float* __restrict__ b7)
{
    __shared__ short finW[4 * 80 * 2];     //  1,280 B
    __shared__ short aW[4 * 504 * 16];     // 64,512 B (a0..a6 packed)

    const int tid = threadIdx.x, lane = tid & 63, wv = tid >> 6;
    const int tx0 = blockIdx.x * 64, Y0 = blockIdx.y * STRIPH;
    const long long b = blockIdx.z;
    const float* pa = p0 + b * s0;
    const float* pb = p1 + b * s1;
    const float* xb = xsrc + b * xstride;
    float* ob = outp + b * (long long)HWSZ;

    const int arow = lane & 15, grp = lane >> 4, lx = lane & 15;
    const int cib = (grp & 1) * 8, kofb = grp >> 1;
    const int c0 = grp * 4;

    // per-wave window geometry (layer wv): in = window wv-1, out = window wv
    const short* inw = aW + 64 * (wv - 1) * (80 - wv);   // valid for wv>=1
    short* outw = aW + 64 * wv * (79 - wv);              // valid for wv<=6
    const int IW = 80 - 2 * wv, OW = 78 - 2 * wv;

    // per-wave weight fragments + tap offsets
    bfrag8 myf[5];
    int dys[5], dxs[5];
    float mb0 = 0.f, mb1 = 0.f, mb2 = 0.f, mb3 = 0.f;
#pragma unroll
    for (int s = 0; s < 5; ++s) {
        const int koff = 2 * s + kofb;
        const int kc = (koff < 9) ? koff : 8;
        dys[s] = kc / 3; dxs[s] = kc - dys[s] * 3;
#pragma unroll
        for (int j = 0; j < 8; ++j) myf[s][j] = 0;
    }
    if (wv == 0) {
#pragma unroll
        for (int j = 0; j < 8; ++j) {
            const int k = grp * 8 + j;
            myf[0][j] = (k < 18) ? f2bf(w0[arow * 18 + (k & 1) * 9 + (k >> 1)])
                                 : (short)0;
        }
        mb0 = b0[c0]; mb1 = b0[c0 + 1]; mb2 = b0[c0 + 2]; mb3 = b0[c0 + 3];
    } else {
        const float* wp = (wv == 1) ? w1 : (wv == 2) ? w2 : (wv == 3) ? w3 :
                          (wv == 4) ? w4 : (wv == 5) ? w5 : (wv == 6) ? w6 : w7;
        const float* bp = (wv == 1) ? b1 : (wv == 2) ? b2 : (wv == 3) ? b3 :
                          (wv == 4) ? b4 : (wv == 5) ? b5 : (wv == 6) ? b6 : b7;
        const bool rmask = (wv < 7) || (arow < 3);
#pragma unroll
        for (int s = 0; s < 5; ++s) {
            const int koff = 2 * s + kofb;
#pragma unroll
            for (int j = 0; j < 8; ++j)
                myf[s][j] = (rmask && koff < 9)
                              ? f2bf(wp[(arow * 16 + cib + j) * 9 + koff])
                              : (short)0;
        }
        if (wv == 7) {
            mb0 = (grp == 0) ? bp[0] : 0.f;
            mb1 = (grp == 0) ? bp[1] : 0.f;
            mb2 = (grp == 0) ? bp[2] : 0.f;
        } else {
            mb0 = bp[c0]; mb1 = bp[c0 + 1]; mb2 = bp[c0 + 2]; mb3 = bp[c0 + 3];
        }
    }

    // wave-7 hoisted staging geometry (ci identical for all 3 elements)
    const int sxx0 = lane >> 1, sci0 = lane & 1;
    const float* sp0 = sci0 ? pb : pa;
    const int sgx0 = tx0 - 8 + sxx0;
    const int sgx1 = sgx0 + 32;
    const int sgx2 = sgx0 + 64;
    const bool gok0 = ((unsigned)sgx0 < (unsigned)WW);
    const bool gok1 = ((unsigned)sgx1 < (unsigned)WW);
    const bool gok2 = (lane < 32) && ((unsigned)sgx2 < (unsigned)WW);

    // generic conv row (layers 1..6): inw/IW -> outw/OW, global row gr
    auto CONVG = [&](int gr) {
        const bool rok = ((unsigned)gr < (unsigned)HH);
        const int halo = (OW - 64) >> 1;
        const int rslot = (gr & 3) * OW;
        const int rm1 = ((gr - 1) & 3) * IW, r00 = (gr & 3) * IW,
                  rp1 = ((gr + 1) & 3) * IW;
        __builtin_amdgcn_s_setprio(1);
#pragma unroll
        for (int c = 0; c < 5; ++c) {
            const int xr = c * 16 + lx;
            const int xc = (c < 4) ? xr : ((xr < OW) ? xr : (OW - 1));
            f32x4 a = { mb0, mb1, mb2, mb3 };
#pragma unroll
            for (int s = 0; s < 5; ++s) {
                const int rof = (dys[s] == 0) ? rm1 : ((dys[s] == 2) ? rp1 : r00);
                const bfrag8 q = *(const bfrag8*)&inw[(rof + xc + dxs[s]) * 16 + cib];
                a = __builtin_amdgcn_mfma_f32_16x16x32_bf16(myf[s], q, a, 0, 0, 0);
            }
            if (xr < OW) {
                const int gx = tx0 - halo + xr;
                const bool ok = rok && ((unsigned)gx < (unsigned)WW);
                short4v st;
#pragma unroll
                for (int i = 0; i < 4; ++i) {
                    const float r = fmaxf(a[i], 0.01f * a[i]);   // leaky
                    st[i] = ok ? f2bf(r) : (short)0;
                }
                *(short4v*)&outw[(rslot + xr) * 16 + c0] = st;
            }
        }
        __builtin_amdgcn_s_setprio(0);
    };

    // L0 row (wave 0): fin gather (K=18, paired u32 reads) -> window 0
    auto L0ROW = [&](int gr) {
        const bool rok = ((unsigned)gr < (unsigned)HH);
        const int rslot = (gr & 3) * 78;
        const int rm1 = ((gr - 1) & 3) * 80, r00 = (gr & 3) * 80,
                  rp1 = ((gr + 1) & 3) * 80;
        short* a0w = aW;   // window 0 at offset 0
        __builtin_amdgcn_s_setprio(1);
#pragma unroll
        for (int c = 0; c < 5; ++c) {
            const int xr = c * 16 + lx;
            const int xc = (c < 4) ? xr : ((xr < 78) ? xr : 77);
            bfrag8 bf;
#pragma unroll
            for (int t = 0; t < 4; ++t) {
                const int k = grp * 8 + 2 * t;     // even; k,k+1 share tap
                if (k < 18) {
                    const int tap = k >> 1, dy = tap / 3, dx = tap - dy * 3;
                    const int ro = (dy == 0) ? rm1 : ((dy == 2) ? rp1 : r00);
                    const unsigned u = *(const unsigned*)&finW[(ro + xc + dx) * 2];
                    bf[2 * t]     = (short)(u & 0xffffu);
                    bf[2 * t + 1] = (short)(u >> 16);
                } else {
                    bf[2 * t] = 0; bf[2 * t + 1] = 0;
                }
            }
            f32x4 a = { mb0, mb1, mb2, mb3 };
            a = __builtin_amdgcn_mfma_f32_16x16x32_bf16(myf[0], bf, a, 0, 0, 0);
            if (xr < 78) {
                const int gx = tx0 - 7 + xr;
                const bool ok = rok && ((unsigned)gx < (unsigned)WW);
                short4v st;
#pragma unroll
                for (int i = 0; i < 4; ++i) {
                    const float r = fmaxf(a[i], 0.01f * a[i]);   // leaky
                    st[i] = ok ? f2bf(r) : (short)0;
                }
                *(short4v*)&a0w[(rslot + xr) * 16 + c0] = st;
            }
        }
        __builtin_amdgcn_s_setprio(0);
    };

    // L7 row (wave 7): window 6 (width 66) -> clip/median3/(x - med) -> global
    auto OUT7 = [&](int gr) {
        const int rm1 = ((gr - 1) & 3) * 66, r00 = (gr & 3) * 66,
                  rp1 = ((gr + 1) & 3) * 66;
        __builtin_amdgcn_s_setprio(1);
#pragma unroll
        for (int c = 0; c < 4; ++c) {
            const int o = c * 16 + lx;
            f32x4 a = { mb0, mb1, mb2, 0.f };
#pragma unroll
            for (int s = 0; s < 5; ++s) {
                const int rof = (dys[s] == 0) ? rm1 : ((dys[s] == 2) ? rp1 : r00);
                const bfrag8 q = *(const bfrag8*)&inw[(rof + o + dxs[s]) * 16 + cib];
                a = __builtin_amdgcn_mfma_f32_16x16x32_bf16(myf[s], q, a, 0, 0, 0);
            }
            if (grp == 0) {
                float y0 = fminf(fmaxf(a[0], -1.f), 1.f);
                float y1 = fminf(fmaxf(a[1], -1.f), 1.f);
                float y2 = fminf(fmaxf(a[2], -1.f), 1.f);
                float med = fmaxf(fminf(y0, fmaxf(y1, y2)), fminf(y1, y2));
                const long long pix = (long long)gr * WW + tx0 + o;
                ob[pix] = xb[pix] - med;
            }
        }
        __builtin_amdgcn_s_setprio(0);
    };

    // wave-7 prefetch registers (row R(S) values, loaded during step S-1)
    float pv0 = 0.f, pv1 = 0.f, pv2 = 0.f;
    if (wv == 7) {
        const int R0 = Y0 - 8;          // row for S=0
        if ((unsigned)R0 < (unsigned)HH) {
            const float* rowp = sp0 + (long long)R0 * WW;
            if (gok0) pv0 = rowp[sgx0];
            if (gok1) pv1 = rowp[sgx1];
            if (gok2) pv2 = rowp[sgx2];
        }
    }

    // main pipeline: NSTEPS steps, ONE barrier each
    for (int S = 0; S < NSTEPS; ++S) {
        if (wv == 7) {
            const int r7 = Y0 - 24 + S;
            if (r7 >= Y0 && r7 <= Y0 + STRIPH - 1) OUT7(r7);
            if (S < STRIPH + 16) {
                const int base = ((Y0 - 8 + S) & 3) * 80;
                finW[(base + sxx0) * 2 + sci0] = f2bf(pv0);
                finW[(base + sxx0 + 32) * 2 + sci0] = f2bf(pv1);
                if (lane < 32)
                    finW[(base + sxx0 + 64) * 2 + sci0] = f2bf(pv2);
            }
            if (S + 1 < STRIPH + 16) {   // prefetch row for step S+1
                const int Rn = Y0 - 7 + S;
                pv0 = 0.f; pv1 = 0.f; pv2 = 0.f;
                if ((unsigned)Rn < (unsigned)HH) {
                    const float* rowp = sp0 + (long long)Rn * WW;
                    if (gok0) pv0 = rowp[sgx0];
                    if (gok1) pv1 = rowp[sgx1];
                    if (gok2) pv2 = rowp[sgx2];
                }
            }
        } else if (wv == 0) {
            const int r0 = Y0 - 10 + S;
            if (r0 >= Y0 - 7 && r0 <= Y0 + STRIPH + 6) L0ROW(r0);
        } else {
            const int r = Y0 - 10 + S - 2 * wv;
            if (r >= Y0 - (7 - wv) && r <= Y0 + STRIPH + 6 - wv) CONVG(r);
        }
        __syncthreads();
    }
}

// ---------------------------------------------------------------------------
// Stats over x: float4 loads, per-wave LDS histograms, SSQ
// ---------------------------------------------------------------------------
__global__ __launch_bounds__(256) void k_stats_x(
    const float* __restrict__ x, unsigned* __restrict__ hist, float* __restrict__ sums)
{
    const int p = blockIdx.y;
    const f32x4* src = (const f32x4*)(x + (long long)p * HWSZ);
    __shared__ unsigned h[4][256];
    for (int i = threadIdx.x; i < 1024; i += 256) ((unsigned*)h)[i] = 0;
    __syncthreads();
    const int wid = threadIdx.x >> 6;

    float ss = 0.f;
    for (int i4 = blockIdx.x * 256 + threadIdx.x; i4 < HWSZ / 4; i4 += gridDim.x * 256) {
        const f32x4 v4 = src[i4];
#pragma unroll
        for (int e = 0; e < 4; ++e) {
            const float v = v4[e];
            ss += v * v;
            if (v >= -1.f && v <= 1.f) {
                int idx = (int)floorf((v + 1.f) * 128.f);
                idx = min(max(idx, 0), 255);
                atomicAdd(&h[wid][idx], 1u);
            }
        }
    }
    __syncthreads();
    const unsigned t = h[0][threadIdx.x] + h[1][threadIdx.x] +
                       h[2][threadIdx.x] + h[3][threadIdx.x];
    if (t) atomicAdd(&hist[p * 256 + threadIdx.x], t);

    float bs = blockSum(ss);
    if (threadIdx.x == 0) atomicAdd(&sums[0], bs);
}

// ---------------------------------------------------------------------------
// Stats over deltas, all 3 planes in one dispatch (z = channel).
// ---------------------------------------------------------------------------
__global__ __launch_bounds__(256) void k_stats_delta(
    const float* __restrict__ planes,
    unsigned* __restrict__ hist, float* __restrict__ sums)
{
    const int b = blockIdx.y, cz = blockIdx.z;
    const float* P = planes + ((long long)cz * BATCH + b) * HWSZ;
    const int row = b * 3 + cz;
    __shared__ unsigned h[4][256];
    for (int i = threadIdx.x; i < 1024; i += 256) ((unsigned*)h)[i] = 0;
    __syncthreads();
    const int wid = threadIdx.x >> 6;

    float ss = 0.f;
    for (int i4 = blockIdx.x * 256 + threadIdx.x; i4 < HWSZ / 4; i4 += gridDim.x * 256) {
        const int i0 = i4 * 4;
        const int y = i0 >> 9, x0 = i0 & (WW - 1);
        const f32x4 cur = ((const f32x4*)P)[i4];
        f32x4 up = { 0.f, 0.f, 0.f, 0.f };
        if (y) up = ((const f32x4*)P)[i4 - (WW / 4)];
        const float left = x0 ? P[i0 - 1] : 0.f;
        const float upl = (x0 && y) ? P[i0 - WW - 1] : 0.f;
#pragma unroll
        for (int e = 0; e < 4; ++e) {
            const float v = cur[e];
            const float n = up[e];
            const float wv = e ? cur[e - 1] : left;
            const float nw = e ? up[e - 1] : upl;
            float pr = n + wv - nw;
            pr = fminf(fmaxf(pr, fminf(n, wv)), fmaxf(n, wv));
            const float d = v - pr;
            ss += d * d;
            if (d >= -1.f && d <= 1.f) {
                int idx = (int)floorf((d + 1.f) * 128.f);
                idx = min(max(idx, 0), 255);
                atomicAdd(&h[wid][idx], 1u);
            }
        }
    }
    __syncthreads();
    const unsigned t = h[0][threadIdx.x] + h[1][threadIdx.x] +
                       h[2][threadIdx.x] + h[3][threadIdx.x];
    if (t) atomicAdd(&hist[row * 256 + threadIdx.x], t);

    float bs = blockSum(ss);
    if (threadIdx.x == 0) atomicAdd(&sums[1], bs);
}

// ---------------------------------------------------------------------------
// Finalize: entropies + the 4 output scalars
// ---------------------------------------------------------------------------
__global__ __launch_bounds__(256) void k_finalize(
    const unsigned* __restrict__ hist0, const unsigned* __restrict__ hist1,
    const float* __restrict__ sums, float* __restrict__ out)
{
    float e0 = 0.f, e1 = 0.f;
    for (int i = threadIdx.x; i < 48 * 256; i += 256) {
        float p0 = (float)hist0[i] * (1.0f / HWSZ);
        if (p0 > 0.f) e0 -= p0 * log2f(p0);
        float p1 = (float)hist1[i] * (1.0f / HWSZ);
        if (p1 > 0.f) e1 -= p1 * log2f(p1);
    }
    float t0 = blockSum(e0);
    float t1 = blockSum(e1);
    if (threadIdx.x == 0) {
        const float N = (float)BATCH * 3.f * (float)HWSZ;
        out[0] = 128.f * sqrtf(sums[1] / N);   // loss1 (deltas)
        out[1] = 128.f * sqrtf(sums[0] / N);   // loss0 (x)
        out[2] = t0 * (1.f / (8.f * 48.f));    // invcr0
        out[3] = t1 * (1.f / (8.f * 48.f));    // invcr1
    }
}

// ---------------------------------------------------------------------------
extern "C" void kernel_launch(void* const* d_in, const int* in_sizes, int n_in,
                              void* d_out, int out_size, void* d_ws, size_t ws_size,
                              hipStream_t stream) {
    const float* x = (const float*)d_in[0];
    const float* w[8];
    const float* bs[8];
    for (int i = 0; i < 8; ++i) {
        w[i]  = (const float*)d_in[1 + 2 * i];
        bs[i] = (const float*)d_in[2 + 2 * i];
    }

    // Workspace: planes (50.33 MB) + hists + sums only — no activation buffer.
    char* ws = (char*)d_ws;
    size_t o = 0;
    float* rpl = (float*)(ws + o); o += (size_t)BATCH * HWSZ * 4;
    float* gpl = (float*)(ws + o); o += (size_t)BATCH * HWSZ * 4;
    float* bpl = (float*)(ws + o); o += (size_t)BATCH * HWSZ * 4;
    unsigned* hist0 = (unsigned*)(ws + o); o += 48 * 256 * 4;
    unsigned* hist1 = (unsigned*)(ws + o); o += 48 * 256 * 4;
    float* sums = (float*)(ws + o); o += 256;

    hipMemsetAsync(hist0, 0, 48 * 256 * 4 * 2 + 256, stream);

    const dim3 gq(WW / 64, HH / STRIPH, BATCH);

    auto predictor = [&](const float* pa, long long sa, const float* pb, long long sb,
                         const float* xs, float* outp) {
        k_pred8<<<gq, 512, 0, stream>>>(
            pa, sa, pb, sb, xs, 3LL * HWSZ, outp,
            w[0], bs[0], w[1], bs[1], w[2], bs[2], w[3], bs[3],
            w[4], bs[4], w[5], bs[5], w[6], bs[6], w[7], bs[7]);
    };

    // r = x_r - pred(g, b);  g = x_g - pred(r, b);  b = x_b - pred(r, g)
    predictor(x + 1LL * HWSZ, 3LL * HWSZ, x + 2LL * HWSZ, 3LL * HWSZ,
              x + 0LL * HWSZ, rpl);
    predictor(rpl, (long long)HWSZ, x + 2LL * HWSZ, 3LL * HWSZ,
              x + 1LL * HWSZ, gpl);
    predictor(rpl, (long long)HWSZ, gpl, (long long)HWSZ,
              x + 2LL * HWSZ, bpl);

    const dim3 sgrid(64, 48);
    k_stats_x<<<sgrid, 256, 0, stream>>>(x, hist0, sums);
    const dim3 dgrid(64, BATCH, 3);
    k_stats_delta<<<dgrid, 256, 0, stream>>>(rpl, hist1, sums);

    k_finalize<<<1, 256, 0, stream>>>(hist0, hist1, sums, (float*)d_out);
}